// Round 6
// baseline (808.602 us; speedup 1.0000x reference)
//
#include <hip/hip_runtime.h>
#include <hip/hip_bf16.h>

// 2-layer GraphSAGE mean-aggr, N=100000, E=1600000, F=128.
// R5: bucketed CSR fill (kills fill_kernel's 122us of random RMW) + bf16 h.
//   - bucket = dst>>7 (782 x 128 nodes); bucket offsets are rowptr[b*128] (free)
//   - pass B: edge -> packed (src<<7|dst&127) into bucket-contiguous staging
//   - pass C: block/bucket, 128 LDS cursors, local permute into csr_src
//   - h stored bf16 in xb (A-op is bf16 anyway; halves mean2 gather + GEMM1 writes)
//   - fallback (small ws): R4 structure (fp32 x gather, fp32 h in d_out)

#define N_NODES 100000
#define N_EDGES 1600000
#define F 128
#define NB 391        // ceil(N/256) scan blocks
#define NBK 782       // ceil(N/128) buckets

typedef __attribute__((ext_vector_type(8))) short short8;
typedef __attribute__((ext_vector_type(4))) float f32x4;

__device__ __forceinline__ unsigned short f2bf(float f) {
    union { __hip_bfloat16 h; unsigned short u; } cv;
    cv.h = __float2bfloat16(f);
    return cv.u;
}
__device__ __forceinline__ float bf2f(unsigned short u) {
    return __uint_as_float(((unsigned)u) << 16);
}

// ---------------- CSR build ----------------
__global__ __launch_bounds__(256) void hist_kernel(
    const int* __restrict__ dst, int* __restrict__ deg_i, int E)
{
    int e = blockIdx.x * 256 + threadIdx.x;
    if (e < E) atomicAdd(&deg_i[dst[e]], 1);
}

__global__ __launch_bounds__(256) void partial_sum_kernel(
    const int* __restrict__ deg_i, int* __restrict__ partial, int N)
{
    int i = blockIdx.x * 256 + threadIdx.x;
    int d = (i < N) ? deg_i[i] : 0;
#pragma unroll
    for (int off = 32; off > 0; off >>= 1) d += __shfl_down(d, off, 64);
    __shared__ int ws[4];
    if ((threadIdx.x & 63) == 0) ws[threadIdx.x >> 6] = d;
    __syncthreads();
    if (threadIdx.x == 0) partial[blockIdx.x] = ws[0] + ws[1] + ws[2] + ws[3];
}

__global__ __launch_bounds__(512) void scan_partial_kernel(int* partial)
{
    __shared__ int s[512];
    int t = threadIdx.x;
    s[t] = (t < NB) ? partial[t] : 0;
    __syncthreads();
#pragma unroll
    for (int off = 1; off < 512; off <<= 1) {
        int v = (t >= off) ? s[t - off] : 0;
        __syncthreads();
        s[t] += v;
        __syncthreads();
    }
    partial[t] = (t == 0) ? 0 : s[t - 1];
}

__global__ __launch_bounds__(256) void rowptr_kernel(
    const int* __restrict__ deg_i, const int* __restrict__ partial,
    int* __restrict__ rowptr, int N)
{
    __shared__ int s[256];
    int t = threadIdx.x;
    int i = blockIdx.x * 256 + t;
    int d = (i < N) ? deg_i[i] : 0;
    s[t] = d;
    __syncthreads();
#pragma unroll
    for (int off = 1; off < 256; off <<= 1) {
        int v = (t >= off) ? s[t - off] : 0;
        __syncthreads();
        s[t] += v;
        __syncthreads();
    }
    if (i < N) rowptr[i] = partial[blockIdx.x] + s[t] - d;   // exclusive
}

__global__ __launch_bounds__(256) void bcur_init_kernel(
    const int* __restrict__ rowptr, int* __restrict__ bcur)
{
    int b = blockIdx.x * 256 + threadIdx.x;
    if (b < NBK) bcur[b] = rowptr[b << 7];
}

// pass B: edge -> bucket-contiguous staging, packed (src<<7 | dst&127)
__global__ __launch_bounds__(256) void bucket_scatter_kernel(
    const int* __restrict__ src, const int* __restrict__ dst,
    int* __restrict__ bcur, unsigned* __restrict__ staging, int E)
{
    int e = blockIdx.x * 256 + threadIdx.x;
    if (e < E) {
        int d = dst[e];
        int pos = atomicAdd(&bcur[d >> 7], 1);
        staging[pos] = ((unsigned)src[e] << 7) | (unsigned)(d & 127);
    }
}

// pass C: one block per bucket, LDS cursors, write csr_src within bucket range
__global__ __launch_bounds__(256) void bucket_fill_kernel(
    const unsigned* __restrict__ staging, const int* __restrict__ rowptr,
    int* __restrict__ csr_src, int N, int E)
{
    __shared__ int cur[128];
    int b = blockIdx.x;
    int base_node = b << 7;
    int t = threadIdx.x;
    if (t < 128) {
        int node = base_node + t;
        cur[t] = (node < N) ? rowptr[node] : 0;
    }
    __syncthreads();
    int start = rowptr[base_node];
    int end = (base_node + 128 < N) ? rowptr[base_node + 128] : E;
    for (int e = start + t; e < end; e += 256) {
        unsigned u = staging[e];
        int p = atomicAdd(&cur[u & 127], 1);
        csr_src[p] = (int)(u >> 7);
    }
}

// ---------------- weight transpose+cast: Wt[layer][col][k] bf16 ----------------
__global__ __launch_bounds__(256) void wt_kernel(
    const float* __restrict__ Wl1, const float* __restrict__ Wr1,
    const float* __restrict__ Wl2, const float* __restrict__ Wr2,
    unsigned short* __restrict__ wt)
{
    int e = blockIdx.x * 256 + threadIdx.x;   // 0..65535
    int layer = e >> 15;
    int idx = e & 32767;
    int k = idx >> 7;      // 0..255
    int c = idx & 127;
    const float* W = (layer == 0) ? (k < 128 ? Wl1 : Wr1)
                                  : (k < 128 ? Wl2 : Wr2);
    float v = W[(k & 127) * 128 + c];
    wt[layer * 32768 + c * 256 + k] = f2bf(v);
}

// ---------------- cast x -> bf16 ----------------
__global__ __launch_bounds__(256) void cast_kernel(
    const float* __restrict__ x, unsigned short* __restrict__ xb, int total4)
{
    int i = blockIdx.x * 256 + threadIdx.x;
    if (i >= total4) return;
    float4 v = ((const float4*)x)[i];
    unsigned lo = ((unsigned)f2bf(v.y) << 16) | f2bf(v.x);
    unsigned hi = ((unsigned)f2bf(v.w) << 16) | f2bf(v.z);
    ((uint2*)xb)[i] = make_uint2(lo, hi);
}

// ---------------- aggregate: mean over in-neighbors, bf16 out ----------------
template <bool SRC_BF16>
__global__ __launch_bounds__(256) void csr_mean_kernel(
    const void* __restrict__ feat, const int* __restrict__ rowptr,
    const int* __restrict__ deg_i, const int* __restrict__ csr_src,
    unsigned int* __restrict__ mean, int N)
{
    int n = blockIdx.x * 4 + (threadIdx.x >> 6);
    int lane = threadIdx.x & 63;
    if (n >= N) return;
    int start = rowptr[n];
    int dg = deg_i[n];
    int end = start + dg;
    float ax = 0.f, ay = 0.f;
    int e = start;
    for (; e + 1 < end; e += 2) {
        int s0 = csr_src[e], s1 = csr_src[e + 1];
        if (SRC_BF16) {
            unsigned u0 = ((const unsigned*)feat)[s0 * 64 + lane];
            unsigned u1 = ((const unsigned*)feat)[s1 * 64 + lane];
            ax += bf2f((unsigned short)u0) + bf2f((unsigned short)u1);
            ay += bf2f((unsigned short)(u0 >> 16)) + bf2f((unsigned short)(u1 >> 16));
        } else {
            float2 v0 = ((const float2*)feat)[s0 * 64 + lane];
            float2 v1 = ((const float2*)feat)[s1 * 64 + lane];
            ax += v0.x + v1.x;
            ay += v0.y + v1.y;
        }
    }
    if (e < end) {
        int s0 = csr_src[e];
        if (SRC_BF16) {
            unsigned u0 = ((const unsigned*)feat)[s0 * 64 + lane];
            ax += bf2f((unsigned short)u0);
            ay += bf2f((unsigned short)(u0 >> 16));
        } else {
            float2 v0 = ((const float2*)feat)[s0 * 64 + lane];
            ax += v0.x;
            ay += v0.y;
        }
    }
    float r = 1.0f / fmaxf((float)dg, 1.0f);
    mean[n * 64 + lane] = ((unsigned)f2bf(ay * r) << 16) | f2bf(ax * r);
}

// ---------------- MFMA GEMM: out = [mean|x] @ Wt^T + bias (+relu) ----------------
// 256 thr = 4 waves; block computes 64 rows x 128 cols; K=256 in 4 chunks of 64.
// Aliasing-safe (xin==outb or xin==outp): block reads only its own rows, all
// global reads complete before the final __syncthreads, epilogue writes after.
template <bool RELU, bool XSRC_BF16, bool OUT_BF16>
__global__ __launch_bounds__(256) void sage_gemm_mfma(
    const unsigned short* __restrict__ meanb,
    const void* __restrict__ xin,
    const unsigned short* __restrict__ wt,   // [128 cols][256 k] bf16
    const float* __restrict__ bias,
    float* __restrict__ outp, unsigned short* __restrict__ outb, int N)
{
    __shared__ unsigned short As[64][72];    // stride 144 B: 16B-aligned, conflict-free b128
    __shared__ unsigned short Bs[128][72];

    const int t = threadIdx.x;
    const int block_row = blockIdx.x * 64;
    const int lane = t & 63;
    const int w = t >> 6;
    const int m = lane & 15;
    const int kq = lane >> 4;

    f32x4 acc[8];
#pragma unroll
    for (int i = 0; i < 8; ++i) acc[i] = (f32x4){0.f, 0.f, 0.f, 0.f};

    for (int chunk = 0; chunk < 4; ++chunk) {
        const bool is_mean = (chunk < 2);
        const int kbase = (chunk & 1) * 64;

        // ---- A tile: 64 rows x 64 k (each thread: 16 bf16 = 32 B) ----
        {
            int row_l = t >> 2;
            int seg = t & 3;
            int grow = block_row + row_l;
            unsigned short* dstp = &As[row_l][seg * 16];
            if (grow < N) {
                if (is_mean) {
                    const uint4* p = (const uint4*)(meanb + (size_t)grow * F + kbase + seg * 16);
                    ((uint4*)dstp)[0] = p[0];
                    ((uint4*)dstp)[1] = p[1];
                } else if (XSRC_BF16) {
                    const uint4* p = (const uint4*)((const unsigned short*)xin +
                                                    (size_t)grow * F + kbase + seg * 16);
                    ((uint4*)dstp)[0] = p[0];
                    ((uint4*)dstp)[1] = p[1];
                } else {
                    const float4* p = (const float4*)((const float*)xin +
                                                      (size_t)grow * F + kbase + seg * 16);
#pragma unroll
                    for (int q = 0; q < 4; ++q) {
                        float4 v = p[q];
                        unsigned lo = ((unsigned)f2bf(v.y) << 16) | f2bf(v.x);
                        unsigned hi = ((unsigned)f2bf(v.w) << 16) | f2bf(v.z);
                        ((unsigned*)dstp)[q * 2]     = lo;
                        ((unsigned*)dstp)[q * 2 + 1] = hi;
                    }
                }
            } else {
                uint4 z = make_uint4(0, 0, 0, 0);
                ((uint4*)dstp)[0] = z;
                ((uint4*)dstp)[1] = z;
            }
        }
        // ---- B tile: 128 cols x 64 k from Wt (each thread: 32 bf16 = 64 B) ----
        {
            int c = t >> 1;
            int half = t & 1;
            const uint4* p = (const uint4*)(wt + c * 256 + chunk * 64 + half * 32);
            unsigned short* dstp = &Bs[c][half * 32];
            ((uint4*)dstp)[0] = p[0];
            ((uint4*)dstp)[1] = p[1];
            ((uint4*)dstp)[2] = p[2];
            ((uint4*)dstp)[3] = p[3];
        }
        __syncthreads();

        // ---- MFMA: A[m=lane&15][k=(lane>>4)*8+j], B[k][n=lane&15] ----
#pragma unroll
        for (int ks = 0; ks < 2; ++ks) {
            short8 a = *(const short8*)&As[w * 16 + m][ks * 32 + kq * 8];
#pragma unroll
            for (int tt = 0; tt < 8; ++tt) {
                short8 b = *(const short8*)&Bs[tt * 16 + m][ks * 32 + kq * 8];
                acc[tt] = __builtin_amdgcn_mfma_f32_16x16x32_bf16(a, b, acc[tt], 0, 0, 0);
            }
        }
        __syncthreads();
    }

    // ---- epilogue: C/D row=(lane>>4)*4+reg, col=lane&15 ----
    float bb[8];
#pragma unroll
    for (int tt = 0; tt < 8; ++tt) bb[tt] = bias[tt * 16 + m];
    int rbase = block_row + w * 16 + kq * 4;
#pragma unroll
    for (int r = 0; r < 4; ++r) {
        int grow = rbase + r;
        if (grow < N) {
#pragma unroll
            for (int tt = 0; tt < 8; ++tt) {
                float v = acc[tt][r] + bb[tt];
                if (RELU) v = fmaxf(v, 0.f);
                if (OUT_BF16)
                    outb[(size_t)grow * F + tt * 16 + m] = f2bf(v);
                else
                    outp[(size_t)grow * F + tt * 16 + m] = v;
            }
        }
    }
}

extern "C" void kernel_launch(void* const* d_in, const int* in_sizes, int n_in,
                              void* d_out, int out_size, void* d_ws, size_t ws_size,
                              hipStream_t stream) {
    const float* x    = (const float*)d_in[0];
    const int*   ei   = (const int*)d_in[1];    // int32 (harness converts int64)
    const float* W_l1 = (const float*)d_in[2];
    const float* W_r1 = (const float*)d_in[3];
    const float* b1   = (const float*)d_in[4];
    const float* W_l2 = (const float*)d_in[5];
    const float* W_r2 = (const float*)d_in[6];
    const float* b2   = (const float*)d_in[7];
    float* out        = (float*)d_out;

    const int N = N_NODES;
    const int E = N_EDGES;
    const int* srcv = ei;
    const int* dstv = ei + E;

    // ---- workspace layout (bytes) ----
    const size_t rowptr_off = 401408;            // deg: [0, 401408)
    const size_t part_off   = 802816;            // 2048 B
    const size_t bcur_off   = 804864;            // 3128 B -> pad
    const size_t csr_off    = 808960;            // int[1.6M] = 6.4 MB -> 7208960
    const size_t wt_off     = 7208960;           // bf16[2][128][256] -> 7340032
    const size_t mean_off   = 7340032;           // bf16[N*F] = 25.6 MB -> 32940032
    const size_t xb_off     = 32940032;          // bf16[N*F] = 25.6 MB -> 58540032
    const size_t need_min   = 32940032;
    const size_t need_full  = 58540032;

    if (ws_size < need_min) return;  // clean validation failure as diagnostic
    const bool full = (ws_size >= need_full);

    char* ws = (char*)d_ws;
    int* deg_i   = (int*)ws;
    int* rowptr  = (int*)(ws + rowptr_off);
    int* partial = (int*)(ws + part_off);
    int* bcur    = (int*)(ws + bcur_off);
    int* csr_src = (int*)(ws + csr_off);
    unsigned short* wt    = (unsigned short*)(ws + wt_off);
    unsigned int*   meanu = (unsigned int*)(ws + mean_off);
    const unsigned short* meanb = (const unsigned short*)(ws + mean_off);
    unsigned* staging = (unsigned*)(ws + mean_off);   // aliases mean (consumed first)
    unsigned short* xb = (unsigned short*)(ws + xb_off);

    // ---- CSR build ----
    hipMemsetAsync(deg_i, 0, (size_t)N * sizeof(int), stream);
    hist_kernel<<<dim3((E + 255) / 256), dim3(256), 0, stream>>>(dstv, deg_i, E);
    partial_sum_kernel<<<dim3(NB), dim3(256), 0, stream>>>(deg_i, partial, N);
    scan_partial_kernel<<<dim3(1), dim3(512), 0, stream>>>(partial);
    rowptr_kernel<<<dim3(NB), dim3(256), 0, stream>>>(deg_i, partial, rowptr, N);
    bcur_init_kernel<<<dim3(4), dim3(256), 0, stream>>>(rowptr, bcur);
    bucket_scatter_kernel<<<dim3((E + 255) / 256), dim3(256), 0, stream>>>(
        srcv, dstv, bcur, staging, E);
    bucket_fill_kernel<<<dim3(NBK), dim3(256), 0, stream>>>(
        staging, rowptr, csr_src, N, E);

    // ---- weight prep + x cast ----
    wt_kernel<<<dim3(256), dim3(256), 0, stream>>>(W_l1, W_r1, W_l2, W_r2, wt);
    if (full)
        cast_kernel<<<dim3((N * F / 4 + 255) / 256), dim3(256), 0, stream>>>(x, xb, N * F / 4);

    dim3 ablock(256), agrid((N + 3) / 4);
    dim3 gblock(256), ggrid((N + 63) / 64);

    if (full) {
        // layer 1: mean(xb) -> gemm -> h bf16 into xb (aliasing-safe)
        csr_mean_kernel<true><<<agrid, ablock, 0, stream>>>(xb, rowptr, deg_i, csr_src, meanu, N);
        sage_gemm_mfma<true, true, true><<<ggrid, gblock, 0, stream>>>(
            meanb, xb, wt, b1, nullptr, xb, N);
        // layer 2: mean(h) -> gemm -> fp32 d_out
        csr_mean_kernel<true><<<agrid, ablock, 0, stream>>>(xb, rowptr, deg_i, csr_src, meanu, N);
        sage_gemm_mfma<false, true, false><<<ggrid, gblock, 0, stream>>>(
            meanb, xb, wt + 32768, b2, out, nullptr, N);
    } else {
        // fallback: fp32 x gather, fp32 h in d_out (R4-proven aliasing)
        csr_mean_kernel<false><<<agrid, ablock, 0, stream>>>(x, rowptr, deg_i, csr_src, meanu, N);
        sage_gemm_mfma<true, false, false><<<ggrid, gblock, 0, stream>>>(
            meanb, x, wt, b1, out, nullptr, N);
        csr_mean_kernel<false><<<agrid, ablock, 0, stream>>>(out, rowptr, deg_i, csr_src, meanu, N);
        sage_gemm_mfma<false, false, false><<<ggrid, gblock, 0, stream>>>(
            meanb, out, wt + 32768, b2, out, nullptr, N);
    }
}

// Round 8
// 509.326 us; speedup vs baseline: 1.5876x; 1.5876x over previous
//
#include <hip/hip_runtime.h>
#include <hip/hip_bf16.h>

// 2-layer GraphSAGE mean-aggr, N=100000, E=1600000, F=128.
// R7 = R6 resubmit (R6 hit GPUAcquisitionTimeout; never measured).
// Contention-free bucket permute: R5's bucket_scatter did 1.6M RETURNING
// global atomics on 782 cursors -> ~2046-deep same-address chains @ ~184ns
// = 377us. Replace with block-histogram counting sort:
//   blkhist (LDS hist per 4096-edge block) -> bucket_scan (per-bucket scan
//   across blocks, seeded rowptr[b<<7]) -> scatter w/ LDS cursors (no global
//   same-address atomics) -> bucket_fill (~2us, R5-proven).
// csr_mean + MFMA GEMM unchanged from R4 (proven).
// ws evidence: ws_size in [33.34MB, 58.54MB) -> xb tier removed;
// blkhist/bbase/staging alias into mean region (consumed before mean written).
// Layout total 32.93MB < proven 33.34MB.

#define N_NODES 100000
#define N_EDGES 1600000
#define F 128
#define NB 391        // ceil(N/256) scan blocks
#define NBK 782       // ceil(N/128) buckets (128 nodes each)
#define NSB 391       // scatter blocks (4096 edges each)

typedef __attribute__((ext_vector_type(8))) short short8;
typedef __attribute__((ext_vector_type(4))) float f32x4;

__device__ __forceinline__ unsigned short f2bf(float f) {
    union { __hip_bfloat16 h; unsigned short u; } cv;
    cv.h = __float2bfloat16(f);
    return cv.u;
}
__device__ __forceinline__ float bf2f(unsigned short u) {
    return __uint_as_float(((unsigned)u) << 16);
}

// ---------------- deg histogram ----------------
__global__ __launch_bounds__(256) void hist_kernel(
    const int* __restrict__ dst, int* __restrict__ deg_i, int E)
{
    int e = blockIdx.x * 256 + threadIdx.x;
    if (e < E) atomicAdd(&deg_i[dst[e]], 1);
}

// ---------------- rowptr (exclusive scan of deg) ----------------
__global__ __launch_bounds__(256) void partial_sum_kernel(
    const int* __restrict__ deg_i, int* __restrict__ partial, int N)
{
    int i = blockIdx.x * 256 + threadIdx.x;
    int d = (i < N) ? deg_i[i] : 0;
#pragma unroll
    for (int off = 32; off > 0; off >>= 1) d += __shfl_down(d, off, 64);
    __shared__ int ws[4];
    if ((threadIdx.x & 63) == 0) ws[threadIdx.x >> 6] = d;
    __syncthreads();
    if (threadIdx.x == 0) partial[blockIdx.x] = ws[0] + ws[1] + ws[2] + ws[3];
}

__global__ __launch_bounds__(512) void scan_partial_kernel(int* partial)
{
    __shared__ int s[512];
    int t = threadIdx.x;
    s[t] = (t < NB) ? partial[t] : 0;
    __syncthreads();
#pragma unroll
    for (int off = 1; off < 512; off <<= 1) {
        int v = (t >= off) ? s[t - off] : 0;
        __syncthreads();
        s[t] += v;
        __syncthreads();
    }
    partial[t] = (t == 0) ? 0 : s[t - 1];
}

__global__ __launch_bounds__(256) void rowptr_kernel(
    const int* __restrict__ deg_i, const int* __restrict__ partial,
    int* __restrict__ rowptr, int N)
{
    __shared__ int s[256];
    int t = threadIdx.x;
    int i = blockIdx.x * 256 + t;
    int d = (i < N) ? deg_i[i] : 0;
    s[t] = d;
    __syncthreads();
#pragma unroll
    for (int off = 1; off < 256; off <<= 1) {
        int v = (t >= off) ? s[t - off] : 0;
        __syncthreads();
        s[t] += v;
        __syncthreads();
    }
    if (i < N) rowptr[i] = partial[blockIdx.x] + s[t] - d;   // exclusive
}

// ---------------- contention-free bucket permute ----------------
// pass 1: per-block bucket histogram. blkhist layout [blk][bucket].
__global__ __launch_bounds__(256) void blkhist_kernel(
    const int* __restrict__ dst, int* __restrict__ blkhist, int E)
{
    __shared__ int h[NBK];
    int t = threadIdx.x, blk = blockIdx.x;
    for (int i = t; i < NBK; i += 256) h[i] = 0;
    __syncthreads();
    int base = blk * 4096;
    int end = min(base + 4096, E);
    for (int e = base + t; e < end; e += 256) atomicAdd(&h[dst[e] >> 7], 1);
    __syncthreads();
    for (int i = t; i < NBK; i += 256) blkhist[blk * NBK + i] = h[i];
}

// pass 2: per-bucket exclusive scan across blocks, seeded with rowptr[b<<7].
__global__ __launch_bounds__(512) void bucket_scan_kernel(
    const int* __restrict__ blkhist, const int* __restrict__ rowptr,
    int* __restrict__ bbase)
{
    __shared__ int s[512];
    int b = blockIdx.x, t = threadIdx.x;
    int v = (t < NSB) ? blkhist[t * NBK + b] : 0;
    s[t] = v;
    __syncthreads();
#pragma unroll
    for (int off = 1; off < 512; off <<= 1) {
        int u = (t >= off) ? s[t - off] : 0;
        __syncthreads();
        s[t] += u;
        __syncthreads();
    }
    if (t < NSB) bbase[t * NBK + b] = rowptr[b << 7] + s[t] - v;
}

// pass 3: scatter via LDS cursors (no global same-address atomics).
__global__ __launch_bounds__(256) void bucket_scatter_kernel(
    const int* __restrict__ src, const int* __restrict__ dst,
    const int* __restrict__ bbase, unsigned* __restrict__ staging, int E)
{
    __shared__ int cur[NBK];
    int t = threadIdx.x, blk = blockIdx.x;
    for (int i = t; i < NBK; i += 256) cur[i] = bbase[blk * NBK + i];
    __syncthreads();
    int base = blk * 4096;
    int end = min(base + 4096, E);
    for (int e = base + t; e < end; e += 256) {
        int d = dst[e];
        int p = atomicAdd(&cur[d >> 7], 1);
        staging[p] = ((unsigned)src[e] << 7) | (unsigned)(d & 127);
    }
}

// pass 4: one block per bucket, 128 LDS cursors, local permute -> csr_src.
__global__ __launch_bounds__(256) void bucket_fill_kernel(
    const unsigned* __restrict__ staging, const int* __restrict__ rowptr,
    int* __restrict__ csr_src, int N, int E)
{
    __shared__ int cur[128];
    int b = blockIdx.x;
    int base_node = b << 7;
    int t = threadIdx.x;
    if (t < 128) {
        int node = base_node + t;
        cur[t] = (node < N) ? rowptr[node] : 0;
    }
    __syncthreads();
    int start = rowptr[base_node];
    int end = (base_node + 128 < N) ? rowptr[base_node + 128] : E;
    for (int e = start + t; e < end; e += 256) {
        unsigned u = staging[e];
        int p = atomicAdd(&cur[u & 127], 1);
        csr_src[p] = (int)(u >> 7);
    }
}

// ---------------- weight transpose+cast: Wt[layer][col][k] bf16 ----------------
__global__ __launch_bounds__(256) void wt_kernel(
    const float* __restrict__ Wl1, const float* __restrict__ Wr1,
    const float* __restrict__ Wl2, const float* __restrict__ Wr2,
    unsigned short* __restrict__ wt)
{
    int e = blockIdx.x * 256 + threadIdx.x;   // 0..65535
    int layer = e >> 15;
    int idx = e & 32767;
    int k = idx >> 7;      // 0..255
    int c = idx & 127;
    const float* W = (layer == 0) ? (k < 128 ? Wl1 : Wr1)
                                  : (k < 128 ? Wl2 : Wr2);
    float v = W[(k & 127) * 128 + c];
    wt[layer * 32768 + c * 256 + k] = f2bf(v);
}

// ---------------- aggregate: mean over in-neighbors (fp32 src), bf16 out ----
__global__ __launch_bounds__(256) void csr_mean_kernel(
    const float* __restrict__ feat, const int* __restrict__ rowptr,
    const int* __restrict__ deg_i, const int* __restrict__ csr_src,
    unsigned int* __restrict__ mean, int N)
{
    int n = blockIdx.x * 4 + (threadIdx.x >> 6);
    int lane = threadIdx.x & 63;
    if (n >= N) return;
    int start = rowptr[n];
    int dg = deg_i[n];
    int end = start + dg;
    float ax = 0.f, ay = 0.f;
    int e = start;
    for (; e + 1 < end; e += 2) {
        int s0 = csr_src[e], s1 = csr_src[e + 1];
        float2 v0 = ((const float2*)feat)[s0 * 64 + lane];
        float2 v1 = ((const float2*)feat)[s1 * 64 + lane];
        ax += v0.x + v1.x;
        ay += v0.y + v1.y;
    }
    if (e < end) {
        int s0 = csr_src[e];
        float2 v0 = ((const float2*)feat)[s0 * 64 + lane];
        ax += v0.x;
        ay += v0.y;
    }
    float r = 1.0f / fmaxf((float)dg, 1.0f);
    mean[n * 64 + lane] = ((unsigned)f2bf(ay * r) << 16) | f2bf(ax * r);
}

// ---------------- MFMA GEMM: out = [mean|x] @ Wt^T + bias (+relu) ----------------
// 256 thr = 4 waves; block computes 64 rows x 128 cols; K=256 in 4 chunks of 64.
// Aliasing-safe (xin==outp): block reads only its own rows before epilogue.
template <bool RELU>
__global__ __launch_bounds__(256) void sage_gemm_mfma(
    const unsigned short* __restrict__ meanb,
    const float* __restrict__ xin,
    const unsigned short* __restrict__ wt,   // [128 cols][256 k] bf16
    const float* __restrict__ bias,
    float* __restrict__ outp, int N)
{
    __shared__ unsigned short As[64][72];    // stride 144 B: 16B-aligned, conflict-free b128
    __shared__ unsigned short Bs[128][72];

    const int t = threadIdx.x;
    const int block_row = blockIdx.x * 64;
    const int lane = t & 63;
    const int w = t >> 6;
    const int m = lane & 15;
    const int kq = lane >> 4;

    f32x4 acc[8];
#pragma unroll
    for (int i = 0; i < 8; ++i) acc[i] = (f32x4){0.f, 0.f, 0.f, 0.f};

    for (int chunk = 0; chunk < 4; ++chunk) {
        const bool is_mean = (chunk < 2);
        const int kbase = (chunk & 1) * 64;

        // ---- A tile: 64 rows x 64 k (each thread: 16 bf16 = 32 B) ----
        {
            int row_l = t >> 2;
            int seg = t & 3;
            int grow = block_row + row_l;
            unsigned short* dstp = &As[row_l][seg * 16];
            if (grow < N) {
                if (is_mean) {
                    const uint4* p = (const uint4*)(meanb + (size_t)grow * F + kbase + seg * 16);
                    ((uint4*)dstp)[0] = p[0];
                    ((uint4*)dstp)[1] = p[1];
                } else {
                    const float4* p = (const float4*)(xin + (size_t)grow * F + kbase + seg * 16);
#pragma unroll
                    for (int q = 0; q < 4; ++q) {
                        float4 v = p[q];
                        unsigned lo = ((unsigned)f2bf(v.y) << 16) | f2bf(v.x);
                        unsigned hi = ((unsigned)f2bf(v.w) << 16) | f2bf(v.z);
                        ((unsigned*)dstp)[q * 2]     = lo;
                        ((unsigned*)dstp)[q * 2 + 1] = hi;
                    }
                }
            } else {
                uint4 z = make_uint4(0, 0, 0, 0);
                ((uint4*)dstp)[0] = z;
                ((uint4*)dstp)[1] = z;
            }
        }
        // ---- B tile: 128 cols x 64 k from Wt (each thread: 32 bf16 = 64 B) ----
        {
            int c = t >> 1;
            int half = t & 1;
            const uint4* p = (const uint4*)(wt + c * 256 + chunk * 64 + half * 32);
            unsigned short* dstp = &Bs[c][half * 32];
            ((uint4*)dstp)[0] = p[0];
            ((uint4*)dstp)[1] = p[1];
            ((uint4*)dstp)[2] = p[2];
            ((uint4*)dstp)[3] = p[3];
        }
        __syncthreads();

        // ---- MFMA: A[m=lane&15][k=(lane>>4)*8+j], B[k][n=lane&15] ----
#pragma unroll
        for (int ks = 0; ks < 2; ++ks) {
            short8 a = *(const short8*)&As[w * 16 + m][ks * 32 + kq * 8];
#pragma unroll
            for (int tt = 0; tt < 8; ++tt) {
                short8 b = *(const short8*)&Bs[tt * 16 + m][ks * 32 + kq * 8];
                acc[tt] = __builtin_amdgcn_mfma_f32_16x16x32_bf16(a, b, acc[tt], 0, 0, 0);
            }
        }
        __syncthreads();
    }

    // ---- epilogue: C/D row=(lane>>4)*4+reg, col=lane&15 ----
    float bb[8];
#pragma unroll
    for (int tt = 0; tt < 8; ++tt) bb[tt] = bias[tt * 16 + m];
    int rbase = block_row + w * 16 + kq * 4;
#pragma unroll
    for (int r = 0; r < 4; ++r) {
        int grow = rbase + r;
        if (grow < N) {
#pragma unroll
            for (int tt = 0; tt < 8; ++tt) {
                float v = acc[tt][r] + bb[tt];
                if (RELU) v = fmaxf(v, 0.f);
                outp[(size_t)grow * F + tt * 16 + m] = v;
            }
        }
    }
}

extern "C" void kernel_launch(void* const* d_in, const int* in_sizes, int n_in,
                              void* d_out, int out_size, void* d_ws, size_t ws_size,
                              hipStream_t stream) {
    const float* x    = (const float*)d_in[0];
    const int*   ei   = (const int*)d_in[1];    // int32 (harness converts int64)
    const float* W_l1 = (const float*)d_in[2];
    const float* W_r1 = (const float*)d_in[3];
    const float* b1   = (const float*)d_in[4];
    const float* W_l2 = (const float*)d_in[5];
    const float* W_r2 = (const float*)d_in[6];
    const float* b2   = (const float*)d_in[7];
    float* out        = (float*)d_out;

    const int N = N_NODES;
    const int E = N_EDGES;
    const int* srcv = ei;
    const int* dstv = ei + E;

    // ---- workspace layout (bytes); ws_size proven >= 33,337,344 ----
    const size_t rowptr_off = 400128;
    const size_t part_off   = 800256;            // 2048 B
    const size_t csr_off    = 802304;            // int[1.6M] = 6.4 MB
    const size_t mean_off   = 7202304;           // bf16[N*F] = 25.6 MB -> 32,802,304
    const size_t wt_off     = 32802304;          // bf16[2][128][256] -> 32,933,376
    const size_t need_min   = 32933376;          // < proven 33,337,344
    // transients aliased into mean region (all consumed before mean is written):
    const size_t blkh_rel   = 0;                 // int[NSB*NBK] = 1,223,048 -> pad
    const size_t bbase_rel  = 1223168;           // int[NSB*NBK]
    const size_t stag_rel   = 2446336;           // uint[1.6M] = 6.4 MB -> 8,846,336 (< 25.6MB)

    if (ws_size < need_min) return;  // clean validation failure as diagnostic

    char* ws = (char*)d_ws;
    int* deg_i   = (int*)ws;
    int* rowptr  = (int*)(ws + rowptr_off);
    int* partial = (int*)(ws + part_off);
    int* csr_src = (int*)(ws + csr_off);
    unsigned int*   meanu = (unsigned int*)(ws + mean_off);
    const unsigned short* meanb = (const unsigned short*)(ws + mean_off);
    int* blkhist = (int*)(ws + mean_off + blkh_rel);
    int* bbase   = (int*)(ws + mean_off + bbase_rel);
    unsigned* staging = (unsigned*)(ws + mean_off + stag_rel);
    unsigned short* wt = (unsigned short*)(ws + wt_off);

    // ---- deg + rowptr ----
    hipMemsetAsync(deg_i, 0, (size_t)N * sizeof(int), stream);
    hist_kernel<<<dim3((E + 255) / 256), dim3(256), 0, stream>>>(dstv, deg_i, E);
    partial_sum_kernel<<<dim3(NB), dim3(256), 0, stream>>>(deg_i, partial, N);
    scan_partial_kernel<<<dim3(1), dim3(512), 0, stream>>>(partial);
    rowptr_kernel<<<dim3(NB), dim3(256), 0, stream>>>(deg_i, partial, rowptr, N);

    // ---- contention-free bucket permute -> csr_src ----
    blkhist_kernel<<<dim3(NSB), dim3(256), 0, stream>>>(dstv, blkhist, E);
    bucket_scan_kernel<<<dim3(NBK), dim3(512), 0, stream>>>(blkhist, rowptr, bbase);
    bucket_scatter_kernel<<<dim3(NSB), dim3(256), 0, stream>>>(
        srcv, dstv, bbase, staging, E);
    bucket_fill_kernel<<<dim3(NBK), dim3(256), 0, stream>>>(
        staging, rowptr, csr_src, N, E);

    // ---- weight prep ----
    wt_kernel<<<dim3(256), dim3(256), 0, stream>>>(W_l1, W_r1, W_l2, W_r2, wt);

    dim3 ablock(256), agrid((N + 3) / 4);
    dim3 gblock(256), ggrid((N + 63) / 64);

    // ---- layer 1 (h fp32 -> d_out) ----
    csr_mean_kernel<<<agrid, ablock, 0, stream>>>(x, rowptr, deg_i, csr_src, meanu, N);
    sage_gemm_mfma<true><<<ggrid, gblock, 0, stream>>>(meanb, x, wt, b1, out, N);

    // ---- layer 2 (reads h from d_out, writes d_out; aliasing-safe) ----
    csr_mean_kernel<<<agrid, ablock, 0, stream>>>(out, rowptr, deg_i, csr_src, meanu, N);
    sage_gemm_mfma<false><<<ggrid, gblock, 0, stream>>>(meanb, out, wt + 32768, b2, out, N);
}